// Round 7
// baseline (7525.349 us; speedup 1.0000x reference)
//
#include <hip/hip_runtime.h>
#include <hip/hip_fp16.h>
#include <math.h>

#define H 128
#define NBK_MAX 2048
#define BSTRIDE 2768            // 64-node buckets: mean 2048 edges, +16 sigma

// ---------------- CSR-less build: bucketed counting sort ----------------
// bucket = dst >> 6 (64 nodes per bucket). packed entry = (local_dst<<17)|src.

__global__ __launch_bounds__(256) void bin_kernel(const int* __restrict__ src,
        const int* __restrict__ dst, int* __restrict__ bucketFill,
        int* __restrict__ packed, int E, int nbk) {
    __shared__ int hcnt[NBK_MAX];
    __shared__ int base[NBK_MAX];
    __shared__ int cur[NBK_MAX];
    int tid = threadIdx.x;
    for (int i = tid; i < nbk; i += 256) { hcnt[i] = 0; cur[i] = 0; }
    __syncthreads();
    int e0 = blockIdx.x * 8192;
    int e1 = min(e0 + 8192, E);
    for (int e = e0 + tid; e < e1; e += 256)
        atomicAdd(&hcnt[dst[e] >> 6], 1);
    __syncthreads();
    for (int i = tid; i < nbk; i += 256) {
        int c = hcnt[i];
        base[i] = c ? atomicAdd(&bucketFill[i], c) : 0;   // claim contiguous chunk
    }
    __syncthreads();
    for (int e = e0 + tid; e < e1; e += 256) {
        int d = dst[e], s = src[e];
        int b = d >> 6;
        int r = atomicAdd(&cur[b], 1);
        packed[(size_t)b * BSTRIDE + base[b] + r] = ((d & 63) << 17) | s;
    }
}

// fine_kernel v2: per bucket, (a) degree counts -> dinv, (b) counting-sort the
// bucket's edges by src>>9 into packed2. Block-monotone src order makes every
// spmm block sweep the gather table coherently.
__global__ __launch_bounds__(256) void fine_kernel(const int* __restrict__ packed,
        const int* __restrict__ bucketFill, int* __restrict__ packed2,
        float* __restrict__ dinv, int N) {
    __shared__ int lcnt[64];
    __shared__ int scnt[256];    // src>>9 bins (<=196 used)
    __shared__ int scur[256];
    int b = blockIdx.x;
    int tid = threadIdx.x;
    int m = bucketFill[b]; if (m > BSTRIDE) m = BSTRIDE;
    int n0 = b << 6;
    if (tid < 64) lcnt[tid] = 0;
    scnt[tid] = 0;
    __syncthreads();
    const int* pk = packed + (size_t)b * BSTRIDE;
    for (int i = tid; i < m; i += 256) {
        int p = pk[i];
        atomicAdd(&lcnt[p >> 17], 1);
        atomicAdd(&scnt[(p & 131071) >> 9], 1);
    }
    __syncthreads();
    int v0 = scnt[tid];
    // inclusive scan (Hillis-Steele, barrier-paired)
    for (int off = 1; off < 256; off <<= 1) {
        int v = 0;
        if (tid >= off) v = scnt[tid - off];
        __syncthreads();
        scnt[tid] += v;
        __syncthreads();
    }
    scur[tid] = scnt[tid] - v0;              // exclusive prefix = bin start
    if (tid < 64) {
        int node = n0 + tid;
        if (node < N) dinv[node] = rsqrtf((float)(lcnt[tid] + 1));   // +1 self loop
    }
    __syncthreads();
    int* pk2 = packed2 + (size_t)b * BSTRIDE;
    for (int i = tid; i < m; i += 256) {
        int p = pk[i];
        int r = atomicAdd(&scur[(p & 131071) >> 9], 1);
        pk2[r] = p;
    }
}

// ---------------- GEMM: chunk-major fp16 table tbl[2][N][64] ----------------
// chunk c holds feats [64c, 64c+64): one 128 B cache line per (node, chunk).

__device__ inline unsigned pack2(float x, float y) {
    __half2 h = __floats2half2_rn(x, y);
    return *(unsigned*)&h;
}

__global__ __launch_bounds__(256) void gemm128_kernel(const float* __restrict__ A,
        const float* __restrict__ W, const float* __restrict__ scale,
        unsigned short* __restrict__ C, int N) {
    __shared__ float As[64][H + 1];
    int tid = threadIdx.x;
    int r0 = blockIdx.x * 64;

    #pragma unroll
    for (int i = 0; i < 8; ++i) {
        int lin = tid + i * 256;          // float4 index, 2048 total
        int r = lin >> 5;                 // 32 float4 per row
        int c4 = (lin & 31) << 2;
        float4 v = make_float4(0.f, 0.f, 0.f, 0.f);
        if (r0 + r < N) v = *(const float4*)&A[(size_t)(r0 + r) * H + c4];
        As[r][c4 + 0] = v.x; As[r][c4 + 1] = v.y;
        As[r][c4 + 2] = v.z; As[r][c4 + 3] = v.w;
    }
    __syncthreads();

    int row = tid & 63;
    int c0 = __builtin_amdgcn_readfirstlane((tid >> 6) << 5);

    float acc[32];
    #pragma unroll
    for (int j = 0; j < 32; ++j) acc[j] = 0.f;

    for (int k = 0; k < H; ++k) {
        float a = As[row][k];
        #pragma unroll
        for (int j = 0; j < 32; ++j)
            acc[j] = fmaf(a, W[k * H + c0 + j], acc[j]);
    }

    int gr = r0 + row;
    if (gr < N) {
        float s = scale[gr];
        int chunk = c0 >> 6;                 // cols c0..c0+31 lie in one chunk
        int cc = c0 & 63;
        uint4* tb = (uint4*)C + (size_t)chunk * N * 8 + (size_t)gr * 8 + (cc >> 3);
        #pragma unroll
        for (int j = 0; j < 32; j += 8) {
            uint4 w;
            w.x = pack2(acc[j + 0] * s, acc[j + 1] * s);
            w.y = pack2(acc[j + 2] * s, acc[j + 3] * s);
            w.z = pack2(acc[j + 4] * s, acc[j + 5] * s);
            w.w = pack2(acc[j + 6] * s, acc[j + 7] * s);
            tb[j >> 3] = w;
        }
    }
}

// ---------------- SpMM: edge-major, LDS accumulators, 2 feature passes ----------------
// Block = one 64-node bucket; all 1563 blocks co-resident (16.6 KB LDS -> 8/CU).
// Edges (src-sorted) swept in order: 8 lanes gather one 128 B table line and
// ds_add into acc[64][65]. Pass p covers feats [64p, 64p+64).

#define ADD8AT(aptr, v)                                                         \
    { float2 f_;                                                                \
      f_ = __half22float2(*(const __half2*)&(v).x);                             \
      atomicAdd((aptr) + 0, f_.x); atomicAdd((aptr) + 1, f_.y);                 \
      f_ = __half22float2(*(const __half2*)&(v).y);                             \
      atomicAdd((aptr) + 2, f_.x); atomicAdd((aptr) + 3, f_.y);                 \
      f_ = __half22float2(*(const __half2*)&(v).z);                             \
      atomicAdd((aptr) + 4, f_.x); atomicAdd((aptr) + 5, f_.y);                 \
      f_ = __half22float2(*(const __half2*)&(v).w);                             \
      atomicAdd((aptr) + 6, f_.x); atomicAdd((aptr) + 7, f_.y); }

__global__ __launch_bounds__(256) void spmm_kernel(const unsigned short* __restrict__ lin,
        const int* __restrict__ packed2, const int* __restrict__ bucketFill,
        const float* __restrict__ dinv, const float* __restrict__ bias,
        float* __restrict__ out, int N) {
    __shared__ float acc[64][65];
    int b = blockIdx.x;
    int tid = threadIdx.x;
    int m = bucketFill[b]; if (m > BSTRIDE) m = BSTRIDE;
    int n0 = b << 6;
    const int* pk2 = packed2 + (size_t)b * BSTRIDE;
    int grp = tid >> 3;                  // 32 edge-groups
    int ln  = tid & 7;                   // lane owns 8 feats (16 B) of the 128 B line

    for (int pass = 0; pass < 2; ++pass) {
        const uint4* tb = (const uint4*)lin + (size_t)pass * N * 8;

        // init acc with self-loop rows (pre-scaled in table)
        #pragma unroll
        for (int k = 0; k < 2; ++k) {
            int idx = tid + k * 256;         // 0..511 = nl*8 + c8
            int nl = idx >> 3, c8 = idx & 7;
            uint4 v = make_uint4(0, 0, 0, 0);
            if (n0 + nl < N) v = tb[(size_t)(n0 + nl) * 8 + c8];
            float* a = &acc[nl][c8 << 3];
            float2 f;
            f = __half22float2(*(const __half2*)&v.x); a[0] = f.x; a[1] = f.y;
            f = __half22float2(*(const __half2*)&v.y); a[2] = f.x; a[3] = f.y;
            f = __half22float2(*(const __half2*)&v.z); a[4] = f.x; a[5] = f.y;
            f = __half22float2(*(const __half2*)&v.w); a[6] = f.x; a[7] = f.y;
        }
        __syncthreads();

        // monotone edge sweep
        int i = grp;
        for (; i + 32 < m; i += 64) {
            int p0 = pk2[i], p1 = pk2[i + 32];
            uint4 v0 = tb[(size_t)(p0 & 131071) * 8 + ln];
            uint4 v1 = tb[(size_t)(p1 & 131071) * 8 + ln];
            float* a0 = &acc[p0 >> 17][ln << 3];
            float* a1 = &acc[p1 >> 17][ln << 3];
            ADD8AT(a0, v0);
            ADD8AT(a1, v1);
        }
        for (; i < m; i += 32) {
            int p = pk2[i];
            uint4 v = tb[(size_t)(p & 131071) * 8 + ln];
            float* a = &acc[p >> 17][ln << 3];
            ADD8AT(a, v);
        }
        __syncthreads();

        // epilogue: dinv scale + bias + tanh + fp32 store
        #pragma unroll
        for (int k = 0; k < 2; ++k) {
            int idx = tid + k * 256;
            int nl = idx >> 3, c8 = idx & 7;
            int node = n0 + nl;
            if (node < N) {
                float d = dinv[node];
                const float* a = &acc[nl][c8 << 3];
                int fb = (pass << 6) + (c8 << 3);
                float4 r0, r1;
                r0.x = tanhf(fmaf(a[0], d, bias[fb + 0]));
                r0.y = tanhf(fmaf(a[1], d, bias[fb + 1]));
                r0.z = tanhf(fmaf(a[2], d, bias[fb + 2]));
                r0.w = tanhf(fmaf(a[3], d, bias[fb + 3]));
                r1.x = tanhf(fmaf(a[4], d, bias[fb + 4]));
                r1.y = tanhf(fmaf(a[5], d, bias[fb + 5]));
                r1.z = tanhf(fmaf(a[6], d, bias[fb + 6]));
                r1.w = tanhf(fmaf(a[7], d, bias[fb + 7]));
                float4* op = (float4*)(out + (size_t)node * H + fb);
                op[0] = r0;
                op[1] = r1;
            }
        }
        __syncthreads();                    // before next pass overwrites acc
    }
}

// ---------------- Classifier: LDS-tiled, 64 rows/block, 4 groups x 10 cols ----------------

__global__ __launch_bounds__(256) void classifier_kernel(const float* __restrict__ h,
        const float* __restrict__ Wc, const float* __restrict__ bc,
        float* __restrict__ out, int N, int Cout) {
    __shared__ float As[64][H + 1];
    int tid = threadIdx.x;
    int r0 = blockIdx.x * 64;

    #pragma unroll
    for (int i = 0; i < 8; ++i) {
        int lin = tid + i * 256;          // float4 index, 2048 total
        int r = lin >> 5;
        int c4 = (lin & 31) << 2;
        float4 v = make_float4(0.f, 0.f, 0.f, 0.f);
        if (r0 + r < N) v = *(const float4*)&h[(size_t)(r0 + r) * H + c4];
        As[r][c4 + 0] = v.x; As[r][c4 + 1] = v.y;
        As[r][c4 + 2] = v.z; As[r][c4 + 3] = v.w;
    }
    __syncthreads();

    int row = tid & 63;
    int c0 = __builtin_amdgcn_readfirstlane((tid >> 6) * 10);   // 4 groups x 10 cols = 40

    float acc[10];
    #pragma unroll
    for (int j = 0; j < 10; ++j) acc[j] = bc[c0 + j];

    for (int k = 0; k < H; ++k) {
        float a = As[row][k];
        #pragma unroll
        for (int j = 0; j < 10; ++j)
            acc[j] = fmaf(a, Wc[k * Cout + c0 + j], acc[j]);
    }

    int gr = r0 + row;
    if (gr < N) {
        float* orow = out + (size_t)gr * Cout + c0;
        #pragma unroll
        for (int j = 0; j < 10; ++j) orow[j] = acc[j];
    }
}

// ---------------- launch ----------------

extern "C" void kernel_launch(void* const* d_in, const int* in_sizes, int n_in,
                              void* d_out, int out_size, void* d_ws, size_t ws_size,
                              hipStream_t stream) {
    const float* x  = (const float*)d_in[0];
    const int* eidx = (const int*)d_in[1];
    const float* W1 = (const float*)d_in[2];
    const float* b1 = (const float*)d_in[3];
    const float* W2 = (const float*)d_in[4];
    const float* b2 = (const float*)d_in[5];
    const float* W3 = (const float*)d_in[6];
    const float* b3 = (const float*)d_in[7];
    const float* Wc = (const float*)d_in[8];
    const float* bc = (const float*)d_in[9];

    int N    = in_sizes[0] / H;       // 100000
    int E    = in_sizes[1] / 2;       // 3200000
    int Cout = in_sizes[8] / H;       // 40
    int nbk  = (N + 63) >> 6;         // 1563 buckets (64 nodes each)

    const int* srcp = eidx;
    const int* dstp = eidx + E;

    float* out  = (float*)d_out;
    float* hOut = out + (size_t)N * Cout;   // h output region doubles as ping buffer

    char* p = (char*)d_ws;
    float* hAf      = (float*)p;  p += (size_t)N * H * 4;   // 51.2 MB region
    float* dinv     = (float*)p;  p += (size_t)N * 4;
    int*   bFill    = (int*)p;    p += NBK_MAX * 4;
    unsigned short* hA = (unsigned short*)hAf;              // fp16 table [0, 25.6 MB)
    int*   packed   = (int*)hAf;                            // [0, 17.3 MB) consumed pre-gemm
    int*   packed2  = (int*)((char*)hAf + (size_t)26 * 1024 * 1024);  // [26, 43.3 MB)

    int gg = (N + 63) / 64;
    int gb = (E + 8191) / 8192;

    hipMemsetAsync(bFill, 0, (size_t)nbk * 4, stream);
    bin_kernel<<<gb, 256, 0, stream>>>(srcp, dstp, bFill, packed, E, nbk);
    fine_kernel<<<nbk, 256, 0, stream>>>(packed, bFill, packed2, dinv, N);

    // layer 1
    gemm128_kernel<<<gg, 256, 0, stream>>>(x, W1, dinv, hA, N);
    spmm_kernel<<<nbk, 256, 0, stream>>>(hA, packed2, bFill, dinv, b1, hOut, N);
    // layer 2
    gemm128_kernel<<<gg, 256, 0, stream>>>(hOut, W2, dinv, hA, N);
    spmm_kernel<<<nbk, 256, 0, stream>>>(hA, packed2, bFill, dinv, b2, hOut, N);
    // layer 3
    gemm128_kernel<<<gg, 256, 0, stream>>>(hOut, W3, dinv, hA, N);
    spmm_kernel<<<nbk, 256, 0, stream>>>(hA, packed2, bFill, dinv, b3, hOut, N);
    // classifier
    classifier_kernel<<<gg, 256, 0, stream>>>(hOut, Wc, bc, out, N, Cout);
}

// Round 8
// 803.681 us; speedup vs baseline: 9.3636x; 9.3636x over previous
//
#include <hip/hip_runtime.h>
#include <hip/hip_fp16.h>
#include <math.h>

#define H 128
#define BSTRIDE 5120            // packed entries per bucket (mean 4096, +16 sigma)
#define NPH 25                  // src phases: src>>12 -> 0..24 (~4096 nodes = 1 MB slice)

// ---------------- CSR build: bucketed counting sort ----------------
// bucket = dst >> 7 (128 nodes per bucket). packed entry = (local_dst<<17)|src.

__global__ __launch_bounds__(256) void bin_kernel(const int* __restrict__ src,
        const int* __restrict__ dst, int* __restrict__ bucketFill,
        int* __restrict__ packed, int E, int nbk) {
    __shared__ int hcnt[1024];
    __shared__ int base[1024];
    __shared__ int cur[1024];
    int tid = threadIdx.x;
    for (int i = tid; i < nbk; i += 256) { hcnt[i] = 0; cur[i] = 0; }
    __syncthreads();
    int e0 = blockIdx.x * 8192;
    int e1 = min(e0 + 8192, E);
    for (int e = e0 + tid; e < e1; e += 256)
        atomicAdd(&hcnt[dst[e] >> 7], 1);
    __syncthreads();
    for (int i = tid; i < nbk; i += 256) {
        int c = hcnt[i];
        base[i] = c ? atomicAdd(&bucketFill[i], c) : 0;   // claim contiguous chunk
    }
    __syncthreads();
    for (int e = e0 + tid; e < e1; e += 256) {
        int d = dst[e], s = src[e];
        int b = d >> 7;
        int r = atomicAdd(&cur[b], 1);
        packed[b * BSTRIDE + base[b] + r] = ((d & 127) << 17) | s;
    }
}

// fine_kernel: per-node CSR ranges with edges SORTED BY SRC PHASE (src>>12),
// bucket prefix (base) computed IN-BLOCK (replaces the serial 1-block bscan):
// strided sum over bucketFill[0..b) + LDS tree reduce, parallel across blocks.
__global__ __launch_bounds__(256) void fine_kernel(const int* __restrict__ packed,
        const int* __restrict__ bucketFill,
        int* __restrict__ rowptr, int* __restrict__ col, float* __restrict__ dinv,
        int N, int E) {
    __shared__ int cnt[128 * NPH];     // 12.8 KB: per (local_dst, phase) count
    __shared__ int cur[128 * NPH];     // 12.8 KB: running scatter cursor
    __shared__ int lcnt[128], lofs[128];
    __shared__ int red[256];
    int b = blockIdx.x;
    int tid = threadIdx.x;
    int m = bucketFill[b]; if (m > BSTRIDE) m = BSTRIDE;
    int n0 = b << 7;

    // ---- bucket base = sum(bucketFill[0..b)) ----
    int psum = 0;
    for (int i = tid; i < b; i += 256) psum += bucketFill[i];
    red[tid] = psum;
    for (int i = tid; i < 128 * NPH; i += 256) cnt[i] = 0;
    __syncthreads();
    #pragma unroll
    for (int off = 128; off > 0; off >>= 1) {
        if (tid < off) red[tid] += red[tid + off];
        __syncthreads();
    }
    int base = red[0];
    if (b == 0 && tid == 0) rowptr[N] = E;

    const int* pk = packed + (size_t)b * BSTRIDE;
    for (int i = tid; i < m; i += 256) {
        int p = pk[i];
        int ld = p >> 17, s = p & 131071;
        atomicAdd(&cnt[ld * NPH + (s >> 12)], 1);
    }
    __syncthreads();
    if (tid < 128) {
        int t = 0;
        #pragma unroll
        for (int q = 0; q < NPH; ++q) t += cnt[tid * NPH + q];
        lcnt[tid] = t;
    }
    __syncthreads();
    if (tid == 0) {
        int acc = 0;
        #pragma unroll 4
        for (int i = 0; i < 128; ++i) { lofs[i] = acc; acc += lcnt[i]; }
    }
    __syncthreads();
    if (tid < 128) {
        int o = lofs[tid];
        #pragma unroll
        for (int q = 0; q < NPH; ++q) {
            int c = cnt[tid * NPH + q];
            cur[tid * NPH + q] = o;
            o += c;
        }
        int node = n0 + tid;
        if (node < N) {
            rowptr[node] = base + lofs[tid];
            dinv[node] = rsqrtf((float)(lcnt[tid] + 1));   // +1 self loop
        }
    }
    __syncthreads();
    for (int i = tid; i < m; i += 256) {
        int p = pk[i];
        int ld = p >> 17, s = p & 131071;
        int r = atomicAdd(&cur[ld * NPH + (s >> 12)], 1);
        col[base + r] = s;
    }
}

// ---------------- GEMM: C[n,128] = fp16((A[n,128] @ W[128,128]) * scale[n]) ----------------

__device__ inline unsigned pack2(float x, float y) {
    __half2 h = __floats2half2_rn(x, y);
    return *(unsigned*)&h;
}

__global__ __launch_bounds__(256) void gemm128_kernel(const float* __restrict__ A,
        const float* __restrict__ W, const float* __restrict__ scale,
        unsigned short* __restrict__ C, int N) {
    __shared__ float As[64][H + 1];
    int tid = threadIdx.x;
    int r0 = blockIdx.x * 64;

    #pragma unroll
    for (int i = 0; i < 8; ++i) {
        int lin = tid + i * 256;          // float4 index, 2048 total
        int r = lin >> 5;                 // 32 float4 per row
        int c4 = (lin & 31) << 2;
        float4 v = make_float4(0.f, 0.f, 0.f, 0.f);
        if (r0 + r < N) v = *(const float4*)&A[(size_t)(r0 + r) * H + c4];
        As[r][c4 + 0] = v.x; As[r][c4 + 1] = v.y;
        As[r][c4 + 2] = v.z; As[r][c4 + 3] = v.w;
    }
    __syncthreads();

    int row = tid & 63;
    int c0 = __builtin_amdgcn_readfirstlane((tid >> 6) << 5);

    float acc[32];
    #pragma unroll
    for (int j = 0; j < 32; ++j) acc[j] = 0.f;

    for (int k = 0; k < H; ++k) {
        float a = As[row][k];
        #pragma unroll
        for (int j = 0; j < 32; ++j)
            acc[j] = fmaf(a, W[k * H + c0 + j], acc[j]);
    }

    int gr = r0 + row;
    if (gr < N) {
        float s = scale[gr];
        unsigned short* Crow = C + (size_t)gr * H;
        #pragma unroll
        for (int j = 0; j < 32; j += 8) {
            uint4 w;
            w.x = pack2(acc[j + 0] * s, acc[j + 1] * s);
            w.y = pack2(acc[j + 2] * s, acc[j + 3] * s);
            w.z = pack2(acc[j + 4] * s, acc[j + 5] * s);
            w.w = pack2(acc[j + 6] * s, acc[j + 7] * s);
            *(uint4*)&Crow[c0 + j] = w;
        }
    }
}

// ---------------- SpMM pull (fp16 gather table, fp32 accumulate/output) ----------------
// 16 threads/node, each owns 8 features (one 16B uint4 of the 256B fp16 row).

__device__ inline void add8(float* a, uint4 v) {
    float2 f;
    f = __half22float2(*(const __half2*)&v.x); a[0] += f.x; a[1] += f.y;
    f = __half22float2(*(const __half2*)&v.y); a[2] += f.x; a[3] += f.y;
    f = __half22float2(*(const __half2*)&v.z); a[4] += f.x; a[5] += f.y;
    f = __half22float2(*(const __half2*)&v.w); a[6] += f.x; a[7] += f.y;
}

__global__ __launch_bounds__(256) void spmm_kernel(const unsigned short* __restrict__ lin,
        const int* __restrict__ rowptr, const int* __restrict__ col,
        const float* __restrict__ dinv, const float* __restrict__ bias,
        float* __restrict__ out, int N) {
    int tid = threadIdx.x;
    int node = blockIdx.x * 16 + (tid >> 4);
    if (node >= N) return;
    int cq = tid & 15;                                 // 16B chunk within row

    int beg = rowptr[node];
    int end = rowptr[node + 1];

    const uint4* linv = (const uint4*)lin;

    float acc[8];
    {
        uint4 sv = linv[(size_t)node * 16 + cq];       // self loop (pre-scaled)
        float2 f;
        f = __half22float2(*(const __half2*)&sv.x); acc[0] = f.x; acc[1] = f.y;
        f = __half22float2(*(const __half2*)&sv.y); acc[2] = f.x; acc[3] = f.y;
        f = __half22float2(*(const __half2*)&sv.z); acc[4] = f.x; acc[5] = f.y;
        f = __half22float2(*(const __half2*)&sv.w); acc[6] = f.x; acc[7] = f.y;
    }

    int e = beg;
    for (; e + 4 <= end; e += 4) {
        int s0 = col[e], s1 = col[e + 1], s2 = col[e + 2], s3 = col[e + 3];
        uint4 v0 = linv[(size_t)s0 * 16 + cq];
        uint4 v1 = linv[(size_t)s1 * 16 + cq];
        uint4 v2 = linv[(size_t)s2 * 16 + cq];
        uint4 v3 = linv[(size_t)s3 * 16 + cq];
        add8(acc, v0);
        add8(acc, v1);
        add8(acc, v2);
        add8(acc, v3);
    }
    for (; e < end; ++e) {
        uint4 v = linv[(size_t)col[e] * 16 + cq];
        add8(acc, v);
    }

    float d = dinv[node];
    int c8 = cq << 3;
    float4 r0, r1;
    r0.x = tanhf(fmaf(acc[0], d, bias[c8 + 0]));
    r0.y = tanhf(fmaf(acc[1], d, bias[c8 + 1]));
    r0.z = tanhf(fmaf(acc[2], d, bias[c8 + 2]));
    r0.w = tanhf(fmaf(acc[3], d, bias[c8 + 3]));
    r1.x = tanhf(fmaf(acc[4], d, bias[c8 + 4]));
    r1.y = tanhf(fmaf(acc[5], d, bias[c8 + 5]));
    r1.z = tanhf(fmaf(acc[6], d, bias[c8 + 6]));
    r1.w = tanhf(fmaf(acc[7], d, bias[c8 + 7]));
    float4* op = (float4*)out + (size_t)node * 32 + (cq << 1);
    op[0] = r0;
    op[1] = r1;
}

// ---------------- Classifier: LDS-tiled, 64 rows/block, 4 groups x 10 cols ----------------

__global__ __launch_bounds__(256) void classifier_kernel(const float* __restrict__ h,
        const float* __restrict__ Wc, const float* __restrict__ bc,
        float* __restrict__ out, int N, int Cout) {
    __shared__ float As[64][H + 1];
    int tid = threadIdx.x;
    int r0 = blockIdx.x * 64;

    #pragma unroll
    for (int i = 0; i < 8; ++i) {
        int lin = tid + i * 256;          // float4 index, 2048 total
        int r = lin >> 5;
        int c4 = (lin & 31) << 2;
        float4 v = make_float4(0.f, 0.f, 0.f, 0.f);
        if (r0 + r < N) v = *(const float4*)&h[(size_t)(r0 + r) * H + c4];
        As[r][c4 + 0] = v.x; As[r][c4 + 1] = v.y;
        As[r][c4 + 2] = v.z; As[r][c4 + 3] = v.w;
    }
    __syncthreads();

    int row = tid & 63;
    int c0 = __builtin_amdgcn_readfirstlane((tid >> 6) * 10);   // 4 groups x 10 cols = 40

    float acc[10];
    #pragma unroll
    for (int j = 0; j < 10; ++j) acc[j] = bc[c0 + j];

    for (int k = 0; k < H; ++k) {
        float a = As[row][k];
        #pragma unroll
        for (int j = 0; j < 10; ++j)
            acc[j] = fmaf(a, Wc[k * Cout + c0 + j], acc[j]);
    }

    int gr = r0 + row;
    if (gr < N) {
        float* orow = out + (size_t)gr * Cout + c0;
        #pragma unroll
        for (int j = 0; j < 10; ++j) orow[j] = acc[j];
    }
}

// ---------------- launch ----------------

extern "C" void kernel_launch(void* const* d_in, const int* in_sizes, int n_in,
                              void* d_out, int out_size, void* d_ws, size_t ws_size,
                              hipStream_t stream) {
    const float* x  = (const float*)d_in[0];
    const int* eidx = (const int*)d_in[1];
    const float* W1 = (const float*)d_in[2];
    const float* b1 = (const float*)d_in[3];
    const float* W2 = (const float*)d_in[4];
    const float* b2 = (const float*)d_in[5];
    const float* W3 = (const float*)d_in[6];
    const float* b3 = (const float*)d_in[7];
    const float* Wc = (const float*)d_in[8];
    const float* bc = (const float*)d_in[9];

    int N    = in_sizes[0] / H;       // 100000
    int E    = in_sizes[1] / 2;       // 3200000
    int Cout = in_sizes[8] / H;       // 40
    int nbk  = (N + 127) >> 7;        // 782 buckets

    const int* srcp = eidx;
    const int* dstp = eidx + E;

    float* out  = (float*)d_out;
    float* hOut = out + (size_t)N * Cout;   // h output region doubles as ping buffer

    char* p = (char*)d_ws;
    float* hAf      = (float*)p;  p += (size_t)N * H * 4;   // fp16 table lives here (half used)
    int*   col      = (int*)p;    p += (size_t)E * 4;
    int*   rowptr   = (int*)p;    p += (size_t)(N + 1) * 4;
    float* dinv     = (float*)p;  p += (size_t)N * 4;
    int*   bFill    = (int*)p;    p += 1024 * 4;
    unsigned short* hA = (unsigned short*)hAf;
    int*   packed   = (int*)hAf;  // aliases hA: consumed by fine_kernel before gemm1 writes hA

    int gg = (N + 63) / 64;
    int gs = (N + 15) / 16;
    int gb = (E + 8191) / 8192;

    hipMemsetAsync(bFill, 0, (size_t)nbk * 4, stream);
    bin_kernel<<<gb, 256, 0, stream>>>(srcp, dstp, bFill, packed, E, nbk);
    fine_kernel<<<nbk, 256, 0, stream>>>(packed, bFill, rowptr, col, dinv, N, E);

    // layer 1
    gemm128_kernel<<<gg, 256, 0, stream>>>(x, W1, dinv, hA, N);
    spmm_kernel<<<gs, 256, 0, stream>>>(hA, rowptr, col, dinv, b1, hOut, N);
    // layer 2
    gemm128_kernel<<<gg, 256, 0, stream>>>(hOut, W2, dinv, hA, N);
    spmm_kernel<<<gs, 256, 0, stream>>>(hA, rowptr, col, dinv, b2, hOut, N);
    // layer 3
    gemm128_kernel<<<gg, 256, 0, stream>>>(hOut, W3, dinv, hA, N);
    spmm_kernel<<<gs, 256, 0, stream>>>(hA, rowptr, col, dinv, b3, hOut, N);
    // classifier
    classifier_kernel<<<gg, 256, 0, stream>>>(hOut, Wc, bc, out, N, Cout);
}

// Round 9
// 705.333 us; speedup vs baseline: 10.6692x; 1.1394x over previous
//
#include <hip/hip_runtime.h>
#include <hip/hip_fp16.h>
#include <math.h>

#define H 128
#define BSTRIDE 5120            // packed entries per bucket (mean 4096, +16 sigma)
#define NPH 25                  // src phases: src>>12 -> 0..24 (~4096 nodes = 1 MB slice)

typedef _Float16 f16x8 __attribute__((ext_vector_type(8)));
typedef float f32x4 __attribute__((ext_vector_type(4)));

// ---------------- CSR build: bucketed counting sort ----------------
// bucket = dst >> 7 (128 nodes per bucket). packed entry = (local_dst<<17)|src.

__global__ __launch_bounds__(256) void bin_kernel(const int* __restrict__ src,
        const int* __restrict__ dst, int* __restrict__ bucketFill,
        int* __restrict__ packed, int E, int nbk) {
    __shared__ int hcnt[1024];
    __shared__ int base[1024];
    __shared__ int cur[1024];
    int tid = threadIdx.x;
    for (int i = tid; i < nbk; i += 256) { hcnt[i] = 0; cur[i] = 0; }
    __syncthreads();
    int e0 = blockIdx.x * 8192;
    int e1 = min(e0 + 8192, E);
    for (int e = e0 + tid; e < e1; e += 256)
        atomicAdd(&hcnt[dst[e] >> 7], 1);
    __syncthreads();
    for (int i = tid; i < nbk; i += 256) {
        int c = hcnt[i];
        base[i] = c ? atomicAdd(&bucketFill[i], c) : 0;   // claim contiguous chunk
    }
    __syncthreads();
    for (int e = e0 + tid; e < e1; e += 256) {
        int d = dst[e], s = src[e];
        int b = d >> 7;
        int r = atomicAdd(&cur[b], 1);
        packed[b * BSTRIDE + base[b] + r] = ((d & 127) << 17) | s;
    }
}

// fine_kernel: per-node CSR ranges with edges SORTED BY SRC PHASE (src>>12),
// bucket prefix (base) computed in-block (no serial bscan dispatch).
__global__ __launch_bounds__(256) void fine_kernel(const int* __restrict__ packed,
        const int* __restrict__ bucketFill,
        int* __restrict__ rowptr, int* __restrict__ col, float* __restrict__ dinv,
        int N, int E) {
    __shared__ int cnt[128 * NPH];     // 12.8 KB: per (local_dst, phase) count
    __shared__ int cur[128 * NPH];     // 12.8 KB: running scatter cursor
    __shared__ int lcnt[128], lofs[128];
    __shared__ int red[256];
    int b = blockIdx.x;
    int tid = threadIdx.x;
    int m = bucketFill[b]; if (m > BSTRIDE) m = BSTRIDE;
    int n0 = b << 7;

    // ---- bucket base = sum(bucketFill[0..b)) ----
    int psum = 0;
    for (int i = tid; i < b; i += 256) psum += bucketFill[i];
    red[tid] = psum;
    for (int i = tid; i < 128 * NPH; i += 256) cnt[i] = 0;
    __syncthreads();
    #pragma unroll
    for (int off = 128; off > 0; off >>= 1) {
        if (tid < off) red[tid] += red[tid + off];
        __syncthreads();
    }
    int base = red[0];
    if (b == 0 && tid == 0) rowptr[N] = E;

    const int* pk = packed + (size_t)b * BSTRIDE;
    for (int i = tid; i < m; i += 256) {
        int p = pk[i];
        int ld = p >> 17, s = p & 131071;
        atomicAdd(&cnt[ld * NPH + (s >> 12)], 1);
    }
    __syncthreads();
    if (tid < 128) {
        int t = 0;
        #pragma unroll
        for (int q = 0; q < NPH; ++q) t += cnt[tid * NPH + q];
        lcnt[tid] = t;
    }
    __syncthreads();
    if (tid == 0) {
        int acc = 0;
        #pragma unroll 4
        for (int i = 0; i < 128; ++i) { lofs[i] = acc; acc += lcnt[i]; }
    }
    __syncthreads();
    if (tid < 128) {
        int o = lofs[tid];
        #pragma unroll
        for (int q = 0; q < NPH; ++q) {
            int c = cnt[tid * NPH + q];
            cur[tid * NPH + q] = o;
            o += c;
        }
        int node = n0 + tid;
        if (node < N) {
            rowptr[node] = base + lofs[tid];
            dinv[node] = rsqrtf((float)(lcnt[tid] + 1));   // +1 self loop
        }
    }
    __syncthreads();
    for (int i = tid; i < m; i += 256) {
        int p = pk[i];
        int ld = p >> 17, s = p & 131071;
        int r = atomicAdd(&cur[ld * NPH + (s >> 12)], 1);
        col[base + r] = s;
    }
}

// ---------------- GEMM (MFMA fp16): C = fp16((A @ W) * scale[n]) ----------------
// 64 rows x 128 cols per block, 4 waves; wave w owns cols [32w,32w+32).
// A, W^T staged fp16 in LDS (+8 pad -> 16B-aligned rows, near-floor conflicts).
// Frag maps: A lane&15=m, k=8*(lane>>4)+j ; B lane&15=n, same k ;
// C/D col=lane&15, row=4*(lane>>4)+reg [m89-verified].

__global__ __launch_bounds__(256) void gemm128_kernel(const float* __restrict__ A,
        const float* __restrict__ W, const float* __restrict__ scale,
        unsigned short* __restrict__ C, int N) {
    __shared__ _Float16 Ah[64][H + 8];     // 17.4 KB
    __shared__ _Float16 Wt[H][H + 8];      // 34.8 KB  (Wt[n][k] = W[k][n])
    int tid = threadIdx.x;
    int r0 = blockIdx.x * 64;

    // stage A (fp32 -> fp16)
    #pragma unroll
    for (int i = 0; i < 8; ++i) {
        int lin = tid + i * 256;          // float4 index, 2048 total
        int r = lin >> 5;                 // 32 float4 per row
        int c4 = (lin & 31) << 2;
        float4 v = make_float4(0.f, 0.f, 0.f, 0.f);
        if (r0 + r < N) v = *(const float4*)&A[(size_t)(r0 + r) * H + c4];
        _Float16* ap = &Ah[r][c4];
        ap[0] = (_Float16)v.x; ap[1] = (_Float16)v.y;
        ap[2] = (_Float16)v.z; ap[3] = (_Float16)v.w;
    }
    // stage W transposed (fp32 -> fp16)
    #pragma unroll
    for (int i = 0; i < 64; ++i) {
        int lin = i * 256 + tid;          // coalesced read of W
        int k = lin >> 7, n = lin & 127;
        Wt[n][k] = (_Float16)W[lin];
    }
    __syncthreads();

    int wid = tid >> 6;
    int lane = tid & 63;
    int cb = wid << 5;                    // wave col base
    int m16 = lane & 15;
    int kg = lane >> 4;                   // k-group

    f32x4 acc[4][2];
    #pragma unroll
    for (int rt = 0; rt < 4; ++rt)
        #pragma unroll
        for (int ct = 0; ct < 2; ++ct)
            acc[rt][ct] = (f32x4){0.f, 0.f, 0.f, 0.f};

    #pragma unroll
    for (int kc = 0; kc < 4; ++kc) {
        int kbase = kc * 32 + kg * 8;
        f16x8 afr[4], bfr[2];
        #pragma unroll
        for (int rt = 0; rt < 4; ++rt)
            afr[rt] = *(const f16x8*)&Ah[rt * 16 + m16][kbase];
        #pragma unroll
        for (int ct = 0; ct < 2; ++ct)
            bfr[ct] = *(const f16x8*)&Wt[cb + ct * 16 + m16][kbase];
        #pragma unroll
        for (int rt = 0; rt < 4; ++rt)
            #pragma unroll
            for (int ct = 0; ct < 2; ++ct)
                acc[rt][ct] = __builtin_amdgcn_mfma_f32_16x16x32_f16(
                        afr[rt], bfr[ct], acc[rt][ct], 0, 0, 0);
    }

    // epilogue: scale by dinv[row], convert fp16, store
    #pragma unroll
    for (int rt = 0; rt < 4; ++rt) {
        int rowb = r0 + rt * 16 + (lane >> 4) * 4;
        #pragma unroll
        for (int reg = 0; reg < 4; ++reg) {
            int grow = rowb + reg;
            if (grow < N) {
                float s = scale[grow];
                unsigned short* Crow = C + (size_t)grow * H + cb + (lane & 15);
                __half h0 = __float2half_rn(acc[rt][0][reg] * s);
                __half h1 = __float2half_rn(acc[rt][1][reg] * s);
                Crow[0]  = *(unsigned short*)&h0;
                Crow[16] = *(unsigned short*)&h1;
            }
        }
    }
}

// ---------------- SpMM pull (fp16 gather table, fp32 accumulate/output) ----------------
// 16 threads/node, each owns 8 features (one 16B uint4 of the 256B fp16 row).

__device__ inline void add8(float* a, uint4 v) {
    float2 f;
    f = __half22float2(*(const __half2*)&v.x); a[0] += f.x; a[1] += f.y;
    f = __half22float2(*(const __half2*)&v.y); a[2] += f.x; a[3] += f.y;
    f = __half22float2(*(const __half2*)&v.z); a[4] += f.x; a[5] += f.y;
    f = __half22float2(*(const __half2*)&v.w); a[6] += f.x; a[7] += f.y;
}

__global__ __launch_bounds__(256) void spmm_kernel(const unsigned short* __restrict__ lin,
        const int* __restrict__ rowptr, const int* __restrict__ col,
        const float* __restrict__ dinv, const float* __restrict__ bias,
        float* __restrict__ out, int N) {
    int tid = threadIdx.x;
    int node = blockIdx.x * 16 + (tid >> 4);
    if (node >= N) return;
    int cq = tid & 15;                                 // 16B chunk within row

    int beg = rowptr[node];
    int end = rowptr[node + 1];

    const uint4* linv = (const uint4*)lin;

    float acc[8];
    {
        uint4 sv = linv[(size_t)node * 16 + cq];       // self loop (pre-scaled)
        float2 f;
        f = __half22float2(*(const __half2*)&sv.x); acc[0] = f.x; acc[1] = f.y;
        f = __half22float2(*(const __half2*)&sv.y); acc[2] = f.x; acc[3] = f.y;
        f = __half22float2(*(const __half2*)&sv.z); acc[4] = f.x; acc[5] = f.y;
        f = __half22float2(*(const __half2*)&sv.w); acc[6] = f.x; acc[7] = f.y;
    }

    int e = beg;
    for (; e + 4 <= end; e += 4) {
        int s0 = col[e], s1 = col[e + 1], s2 = col[e + 2], s3 = col[e + 3];
        uint4 v0 = linv[(size_t)s0 * 16 + cq];
        uint4 v1 = linv[(size_t)s1 * 16 + cq];
        uint4 v2 = linv[(size_t)s2 * 16 + cq];
        uint4 v3 = linv[(size_t)s3 * 16 + cq];
        add8(acc, v0);
        add8(acc, v1);
        add8(acc, v2);
        add8(acc, v3);
    }
    for (; e < end; ++e) {
        uint4 v = linv[(size_t)col[e] * 16 + cq];
        add8(acc, v);
    }

    float d = dinv[node];
    int c8 = cq << 3;
    float4 r0, r1;
    r0.x = tanhf(fmaf(acc[0], d, bias[c8 + 0]));
    r0.y = tanhf(fmaf(acc[1], d, bias[c8 + 1]));
    r0.z = tanhf(fmaf(acc[2], d, bias[c8 + 2]));
    r0.w = tanhf(fmaf(acc[3], d, bias[c8 + 3]));
    r1.x = tanhf(fmaf(acc[4], d, bias[c8 + 4]));
    r1.y = tanhf(fmaf(acc[5], d, bias[c8 + 5]));
    r1.z = tanhf(fmaf(acc[6], d, bias[c8 + 6]));
    r1.w = tanhf(fmaf(acc[7], d, bias[c8 + 7]));
    float4* op = (float4*)out + (size_t)node * 32 + (cq << 1);
    op[0] = r0;
    op[1] = r1;
}

// ---------------- Classifier: LDS-tiled, 64 rows/block, 4 groups x 10 cols ----------------

__global__ __launch_bounds__(256) void classifier_kernel(const float* __restrict__ h,
        const float* __restrict__ Wc, const float* __restrict__ bc,
        float* __restrict__ out, int N, int Cout) {
    __shared__ float As[64][H + 1];
    int tid = threadIdx.x;
    int r0 = blockIdx.x * 64;

    #pragma unroll
    for (int i = 0; i < 8; ++i) {
        int lin = tid + i * 256;          // float4 index, 2048 total
        int r = lin >> 5;
        int c4 = (lin & 31) << 2;
        float4 v = make_float4(0.f, 0.f, 0.f, 0.f);
        if (r0 + r < N) v = *(const float4*)&h[(size_t)(r0 + r) * H + c4];
        As[r][c4 + 0] = v.x; As[r][c4 + 1] = v.y;
        As[r][c4 + 2] = v.z; As[r][c4 + 3] = v.w;
    }
    __syncthreads();

    int row = tid & 63;
    int c0 = __builtin_amdgcn_readfirstlane((tid >> 6) * 10);   // 4 groups x 10 cols = 40

    float acc[10];
    #pragma unroll
    for (int j = 0; j < 10; ++j) acc[j] = bc[c0 + j];

    for (int k = 0; k < H; ++k) {
        float a = As[row][k];
        #pragma unroll
        for (int j = 0; j < 10; ++j)
            acc[j] = fmaf(a, Wc[k * Cout + c0 + j], acc[j]);
    }

    int gr = r0 + row;
    if (gr < N) {
        float* orow = out + (size_t)gr * Cout + c0;
        #pragma unroll
        for (int j = 0; j < 10; ++j) orow[j] = acc[j];
    }
}

// ---------------- launch ----------------

extern "C" void kernel_launch(void* const* d_in, const int* in_sizes, int n_in,
                              void* d_out, int out_size, void* d_ws, size_t ws_size,
                              hipStream_t stream) {
    const float* x  = (const float*)d_in[0];
    const int* eidx = (const int*)d_in[1];
    const float* W1 = (const float*)d_in[2];
    const float* b1 = (const float*)d_in[3];
    const float* W2 = (const float*)d_in[4];
    const float* b2 = (const float*)d_in[5];
    const float* W3 = (const float*)d_in[6];
    const float* b3 = (const float*)d_in[7];
    const float* Wc = (const float*)d_in[8];
    const float* bc = (const float*)d_in[9];

    int N    = in_sizes[0] / H;       // 100000
    int E    = in_sizes[1] / 2;       // 3200000
    int Cout = in_sizes[8] / H;       // 40
    int nbk  = (N + 127) >> 7;        // 782 buckets

    const int* srcp = eidx;
    const int* dstp = eidx + E;

    float* out  = (float*)d_out;
    float* hOut = out + (size_t)N * Cout;   // h output region doubles as ping buffer

    char* p = (char*)d_ws;
    float* hAf      = (float*)p;  p += (size_t)N * H * 4;   // fp16 table lives here (half used)
    int*   col      = (int*)p;    p += (size_t)E * 4;
    int*   rowptr   = (int*)p;    p += (size_t)(N + 1) * 4;
    float* dinv     = (float*)p;  p += (size_t)N * 4;
    int*   bFill    = (int*)p;    p += 1024 * 4;
    unsigned short* hA = (unsigned short*)hAf;
    int*   packed   = (int*)hAf;  // aliases hA: consumed by fine_kernel before gemm1 writes hA

    int gg = (N + 63) / 64;
    int gs = (N + 15) / 16;
    int gb = (E + 8191) / 8192;

    hipMemsetAsync(bFill, 0, (size_t)nbk * 4, stream);
    bin_kernel<<<gb, 256, 0, stream>>>(srcp, dstp, bFill, packed, E, nbk);
    fine_kernel<<<nbk, 256, 0, stream>>>(packed, bFill, rowptr, col, dinv, N, E);

    // layer 1
    gemm128_kernel<<<gg, 256, 0, stream>>>(x, W1, dinv, hA, N);
    spmm_kernel<<<gs, 256, 0, stream>>>(hA, rowptr, col, dinv, b1, hOut, N);
    // layer 2
    gemm128_kernel<<<gg, 256, 0, stream>>>(hOut, W2, dinv, hA, N);
    spmm_kernel<<<gs, 256, 0, stream>>>(hA, rowptr, col, dinv, b2, hOut, N);
    // layer 3
    gemm128_kernel<<<gg, 256, 0, stream>>>(hOut, W3, dinv, hA, N);
    spmm_kernel<<<gs, 256, 0, stream>>>(hA, rowptr, col, dinv, b3, hOut, N);
    // classifier
    classifier_kernel<<<gg, 256, 0, stream>>>(hOut, Wc, bc, out, N, Cout);
}

// Round 10
// 677.683 us; speedup vs baseline: 11.1045x; 1.0408x over previous
//
#include <hip/hip_runtime.h>
#include <hip/hip_fp16.h>
#include <math.h>

#define H 128
#define COUT 40
#define BSTRIDE 5120            // packed entries per bucket (mean 4096, +16 sigma)
#define NPH 25                  // src phases: src>>12 -> 0..24 (~4096 nodes = 1 MB slice)

typedef _Float16 f16x8 __attribute__((ext_vector_type(8)));
typedef float f32x4 __attribute__((ext_vector_type(4)));

// ---------------- CSR build: bucketed counting sort ----------------
// bucket = dst >> 7 (128 nodes per bucket). packed entry = (local_dst<<17)|src.

__global__ __launch_bounds__(256) void bin_kernel(const int* __restrict__ src,
        const int* __restrict__ dst, int* __restrict__ bucketFill,
        int* __restrict__ packed, int E, int nbk) {
    __shared__ int hcnt[1024];
    __shared__ int base[1024];
    __shared__ int cur[1024];
    int tid = threadIdx.x;
    for (int i = tid; i < nbk; i += 256) { hcnt[i] = 0; cur[i] = 0; }
    __syncthreads();
    int e0 = blockIdx.x * 8192;
    int e1 = min(e0 + 8192, E);
    for (int e = e0 + tid; e < e1; e += 256)
        atomicAdd(&hcnt[dst[e] >> 7], 1);
    __syncthreads();
    for (int i = tid; i < nbk; i += 256) {
        int c = hcnt[i];
        base[i] = c ? atomicAdd(&bucketFill[i], c) : 0;   // claim contiguous chunk
    }
    __syncthreads();
    for (int e = e0 + tid; e < e1; e += 256) {
        int d = dst[e], s = src[e];
        int b = d >> 7;
        int r = atomicAdd(&cur[b], 1);
        packed[b * BSTRIDE + base[b] + r] = ((d & 127) << 17) | s;
    }
}

// fine_kernel: per-node CSR ranges with edges SORTED BY SRC PHASE (src>>12),
// bucket prefix (base) computed in-block (no serial bscan dispatch).
__global__ __launch_bounds__(256) void fine_kernel(const int* __restrict__ packed,
        const int* __restrict__ bucketFill,
        int* __restrict__ rowptr, int* __restrict__ col, float* __restrict__ dinv,
        int N, int E) {
    __shared__ int cnt[128 * NPH];     // 12.8 KB: per (local_dst, phase) count
    __shared__ int cur[128 * NPH];     // 12.8 KB: running scatter cursor
    __shared__ int lcnt[128], lofs[128];
    __shared__ int red[256];
    int b = blockIdx.x;
    int tid = threadIdx.x;
    int m = bucketFill[b]; if (m > BSTRIDE) m = BSTRIDE;
    int n0 = b << 7;

    // ---- bucket base = sum(bucketFill[0..b)) ----
    int psum = 0;
    for (int i = tid; i < b; i += 256) psum += bucketFill[i];
    red[tid] = psum;
    for (int i = tid; i < 128 * NPH; i += 256) cnt[i] = 0;
    __syncthreads();
    #pragma unroll
    for (int off = 128; off > 0; off >>= 1) {
        if (tid < off) red[tid] += red[tid + off];
        __syncthreads();
    }
    int base = red[0];
    if (b == 0 && tid == 0) rowptr[N] = E;

    const int* pk = packed + (size_t)b * BSTRIDE;
    for (int i = tid; i < m; i += 256) {
        int p = pk[i];
        int ld = p >> 17, s = p & 131071;
        atomicAdd(&cnt[ld * NPH + (s >> 12)], 1);
    }
    __syncthreads();
    if (tid < 128) {
        int t = 0;
        #pragma unroll
        for (int q = 0; q < NPH; ++q) t += cnt[tid * NPH + q];
        lcnt[tid] = t;
    }
    __syncthreads();
    if (tid == 0) {
        int acc = 0;
        #pragma unroll 4
        for (int i = 0; i < 128; ++i) { lofs[i] = acc; acc += lcnt[i]; }
    }
    __syncthreads();
    if (tid < 128) {
        int o = lofs[tid];
        #pragma unroll
        for (int q = 0; q < NPH; ++q) {
            int c = cnt[tid * NPH + q];
            cur[tid * NPH + q] = o;
            o += c;
        }
        int node = n0 + tid;
        if (node < N) {
            rowptr[node] = base + lofs[tid];
            dinv[node] = rsqrtf((float)(lcnt[tid] + 1));   // +1 self loop
        }
    }
    __syncthreads();
    for (int i = tid; i < m; i += 256) {
        int p = pk[i];
        int ld = p >> 17, s = p & 131071;
        int r = atomicAdd(&cur[ld * NPH + (s >> 12)], 1);
        col[base + r] = s;
    }
}

// ---------------- GEMM (MFMA fp16): C = fp16((A @ W) * scale[n]) ----------------
// 64 rows x 128 cols per block, 4 waves; wave w owns cols [32w,32w+32).
// A, W^T staged fp16 in LDS (+8 pad -> 16B-aligned rows).
// Frag maps: A lane&15=m, k=8*(lane>>4)+j ; B lane&15=n, same k ;
// C/D col=lane&15, row=4*(lane>>4)+reg [m89-verified].

__device__ inline unsigned pack2(float x, float y) {
    __half2 h = __floats2half2_rn(x, y);
    return *(unsigned*)&h;
}

__device__ inline void gemm_core_and_store(_Float16 (*Ah)[H + 8], _Float16 (*Wt)[H + 8],
        const float* scale, unsigned short* C, int r0, int tid, int N) {
    int wid = tid >> 6;
    int lane = tid & 63;
    int cb = wid << 5;                    // wave col base
    int m16 = lane & 15;
    int kg = lane >> 4;                   // k-group

    f32x4 acc[4][2];
    #pragma unroll
    for (int rt = 0; rt < 4; ++rt)
        #pragma unroll
        for (int ct = 0; ct < 2; ++ct)
            acc[rt][ct] = (f32x4){0.f, 0.f, 0.f, 0.f};

    #pragma unroll
    for (int kc = 0; kc < 4; ++kc) {
        int kbase = kc * 32 + kg * 8;
        f16x8 afr[4], bfr[2];
        #pragma unroll
        for (int rt = 0; rt < 4; ++rt)
            afr[rt] = *(const f16x8*)&Ah[rt * 16 + m16][kbase];
        #pragma unroll
        for (int ct = 0; ct < 2; ++ct)
            bfr[ct] = *(const f16x8*)&Wt[cb + ct * 16 + m16][kbase];
        #pragma unroll
        for (int rt = 0; rt < 4; ++rt)
            #pragma unroll
            for (int ct = 0; ct < 2; ++ct)
                acc[rt][ct] = __builtin_amdgcn_mfma_f32_16x16x32_f16(
                        afr[rt], bfr[ct], acc[rt][ct], 0, 0, 0);
    }

    #pragma unroll
    for (int rt = 0; rt < 4; ++rt) {
        int rowb = r0 + rt * 16 + kg * 4;
        #pragma unroll
        for (int reg = 0; reg < 4; ++reg) {
            int grow = rowb + reg;
            if (grow < N) {
                float s = scale[grow];
                unsigned short* Crow = C + (size_t)grow * H + cb + m16;
                __half h0 = __float2half_rn(acc[rt][0][reg] * s);
                __half h1 = __float2half_rn(acc[rt][1][reg] * s);
                Crow[0]  = *(unsigned short*)&h0;
                Crow[16] = *(unsigned short*)&h1;
            }
        }
    }
}

__global__ __launch_bounds__(256) void gemm128_kernel(const float* __restrict__ A,
        const float* __restrict__ W, const float* __restrict__ scale,
        unsigned short* __restrict__ C, int N) {
    __shared__ _Float16 Ah[64][H + 8];     // 17.4 KB
    __shared__ _Float16 Wt[H][H + 8];      // 34.8 KB  (Wt[n][k] = W[k][n])
    int tid = threadIdx.x;
    int r0 = blockIdx.x * 64;

    #pragma unroll
    for (int i = 0; i < 8; ++i) {
        int lin = tid + i * 256;          // float4 index, 2048 total
        int r = lin >> 5;
        int c4 = (lin & 31) << 2;
        float4 v = make_float4(0.f, 0.f, 0.f, 0.f);
        if (r0 + r < N) v = *(const float4*)&A[(size_t)(r0 + r) * H + c4];
        _Float16* ap = &Ah[r][c4];
        ap[0] = (_Float16)v.x; ap[1] = (_Float16)v.y;
        ap[2] = (_Float16)v.z; ap[3] = (_Float16)v.w;
    }
    #pragma unroll
    for (int i = 0; i < 64; ++i) {
        int lin = i * 256 + tid;
        int k = lin >> 7, n = lin & 127;
        Wt[n][k] = (_Float16)W[lin];
    }
    __syncthreads();
    gemm_core_and_store(Ah, Wt, scale, C, r0, tid, N);
}

// fp16-input variant: A already fp16 row-major [N][128]
__global__ __launch_bounds__(256) void gemm128f16_kernel(const unsigned short* __restrict__ A,
        const float* __restrict__ W, const float* __restrict__ scale,
        unsigned short* __restrict__ C, int N) {
    __shared__ _Float16 Ah[64][H + 8];
    __shared__ _Float16 Wt[H][H + 8];
    int tid = threadIdx.x;
    int r0 = blockIdx.x * 64;

    #pragma unroll
    for (int i = 0; i < 4; ++i) {
        int lin = tid + i * 256;          // uint4 index, 1024 total (16 per row)
        int r = lin >> 4;
        int c8 = (lin & 15) << 3;
        uint4 v = make_uint4(0, 0, 0, 0);
        if (r0 + r < N) v = *(const uint4*)&A[(size_t)(r0 + r) * H + c8];
        *(uint4*)&Ah[r][c8] = v;
    }
    #pragma unroll
    for (int i = 0; i < 64; ++i) {
        int lin = i * 256 + tid;
        int k = lin >> 7, n = lin & 127;
        Wt[n][k] = (_Float16)W[lin];
    }
    __syncthreads();
    gemm_core_and_store(Ah, Wt, scale, C, r0, tid, N);
}

// ---------------- SpMM pull (fp16 gather table, fp32 accumulate) ----------------
// 16 threads/node, each owns 8 features (one 16B uint4 of the 256B fp16 row).

__device__ inline void add8(float* a, uint4 v) {
    float2 f;
    f = __half22float2(*(const __half2*)&v.x); a[0] += f.x; a[1] += f.y;
    f = __half22float2(*(const __half2*)&v.y); a[2] += f.x; a[3] += f.y;
    f = __half22float2(*(const __half2*)&v.z); a[4] += f.x; a[5] += f.y;
    f = __half22float2(*(const __half2*)&v.w); a[6] += f.x; a[7] += f.y;
}

__device__ inline void spmm_gather(const uint4* linv, const int* rowptr,
        const int* col, int node, int cq, float* acc) {
    int beg = rowptr[node];
    int end = rowptr[node + 1];
    {
        uint4 sv = linv[(size_t)node * 16 + cq];       // self loop (pre-scaled)
        float2 f;
        f = __half22float2(*(const __half2*)&sv.x); acc[0] = f.x; acc[1] = f.y;
        f = __half22float2(*(const __half2*)&sv.y); acc[2] = f.x; acc[3] = f.y;
        f = __half22float2(*(const __half2*)&sv.z); acc[4] = f.x; acc[5] = f.y;
        f = __half22float2(*(const __half2*)&sv.w); acc[6] = f.x; acc[7] = f.y;
    }
    int e = beg;
    for (; e + 4 <= end; e += 4) {
        int s0 = col[e], s1 = col[e + 1], s2 = col[e + 2], s3 = col[e + 3];
        uint4 v0 = linv[(size_t)s0 * 16 + cq];
        uint4 v1 = linv[(size_t)s1 * 16 + cq];
        uint4 v2 = linv[(size_t)s2 * 16 + cq];
        uint4 v3 = linv[(size_t)s3 * 16 + cq];
        add8(acc, v0);
        add8(acc, v1);
        add8(acc, v2);
        add8(acc, v3);
    }
    for (; e < end; ++e) {
        uint4 v = linv[(size_t)col[e] * 16 + cq];
        add8(acc, v);
    }
}

// layers 1-2: tanh output stored as fp16 rows (next gemm casts to fp16 anyway)
__global__ __launch_bounds__(256) void spmm_h16_kernel(const unsigned short* __restrict__ lin,
        const int* __restrict__ rowptr, const int* __restrict__ col,
        const float* __restrict__ dinv, const float* __restrict__ bias,
        unsigned short* __restrict__ h16, int N) {
    int tid = threadIdx.x;
    int node = blockIdx.x * 16 + (tid >> 4);
    if (node >= N) return;
    int cq = tid & 15;

    float acc[8];
    spmm_gather((const uint4*)lin, rowptr, col, node, cq, acc);

    float d = dinv[node];
    int c8 = cq << 3;
    float t0 = tanhf(fmaf(acc[0], d, bias[c8 + 0]));
    float t1 = tanhf(fmaf(acc[1], d, bias[c8 + 1]));
    float t2 = tanhf(fmaf(acc[2], d, bias[c8 + 2]));
    float t3 = tanhf(fmaf(acc[3], d, bias[c8 + 3]));
    float t4 = tanhf(fmaf(acc[4], d, bias[c8 + 4]));
    float t5 = tanhf(fmaf(acc[5], d, bias[c8 + 5]));
    float t6 = tanhf(fmaf(acc[6], d, bias[c8 + 6]));
    float t7 = tanhf(fmaf(acc[7], d, bias[c8 + 7]));
    uint4 w;
    w.x = pack2(t0, t1);
    w.y = pack2(t2, t3);
    w.z = pack2(t4, t5);
    w.w = pack2(t6, t7);
    ((uint4*)h16)[(size_t)node * 16 + cq] = w;
}

// layer 3: fp32 h output + fused classifier (out = h @ Wc + bc)
__global__ __launch_bounds__(256) void spmm_fused_kernel(const unsigned short* __restrict__ lin,
        const int* __restrict__ rowptr, const int* __restrict__ col,
        const float* __restrict__ dinv, const float* __restrict__ bias,
        const float* __restrict__ Wc, const float* __restrict__ bc,
        float* __restrict__ hout, float* __restrict__ out, int N) {
    __shared__ float Hs[16][132];          // padded: stride-128 would be 16-way same-bank
    __shared__ float WcS[H * COUT];        // 20.5 KB, row-major [k][c]
    int tid = threadIdx.x;
    int node = blockIdx.x * 16 + (tid >> 4);
    int cq = tid & 15;
    bool act = node < N;

    for (int i = tid; i < H * COUT; i += 256) WcS[i] = Wc[i];

    float acc[8];
    if (act) spmm_gather((const uint4*)lin, rowptr, col, node, cq, acc);

    int nl = tid >> 4;
    int c8 = cq << 3;
    if (act) {
        float d = dinv[node];
        float4 r0, r1;
        r0.x = tanhf(fmaf(acc[0], d, bias[c8 + 0]));
        r0.y = tanhf(fmaf(acc[1], d, bias[c8 + 1]));
        r0.z = tanhf(fmaf(acc[2], d, bias[c8 + 2]));
        r0.w = tanhf(fmaf(acc[3], d, bias[c8 + 3]));
        r1.x = tanhf(fmaf(acc[4], d, bias[c8 + 4]));
        r1.y = tanhf(fmaf(acc[5], d, bias[c8 + 5]));
        r1.z = tanhf(fmaf(acc[6], d, bias[c8 + 6]));
        r1.w = tanhf(fmaf(acc[7], d, bias[c8 + 7]));
        float4* op = (float4*)hout + (size_t)node * 32 + (cq << 1);
        op[0] = r0;
        op[1] = r1;
        *(float4*)&Hs[nl][c8]     = r0;
        *(float4*)&Hs[nl][c8 + 4] = r1;
    }
    __syncthreads();

    // matvec: thread (nl, cq) computes cols cq, cq+16 (+cq+32 if cq<8)
    float s0 = 0.f, s1 = 0.f, s2 = 0.f;
    for (int k = 0; k < H; ++k) {
        float h = Hs[nl][k];
        const float* wr = &WcS[k * COUT];
        s0 = fmaf(h, wr[cq], s0);
        s1 = fmaf(h, wr[cq + 16], s1);
        if (cq < 8) s2 = fmaf(h, wr[cq + 32], s2);
    }
    if (act) {
        float* orow = out + (size_t)node * COUT;
        orow[cq]      = s0 + bc[cq];
        orow[cq + 16] = s1 + bc[cq + 16];
        if (cq < 8) orow[cq + 32] = s2 + bc[cq + 32];
    }
}

// ---------------- launch ----------------

extern "C" void kernel_launch(void* const* d_in, const int* in_sizes, int n_in,
                              void* d_out, int out_size, void* d_ws, size_t ws_size,
                              hipStream_t stream) {
    const float* x  = (const float*)d_in[0];
    const int* eidx = (const int*)d_in[1];
    const float* W1 = (const float*)d_in[2];
    const float* b1 = (const float*)d_in[3];
    const float* W2 = (const float*)d_in[4];
    const float* b2 = (const float*)d_in[5];
    const float* W3 = (const float*)d_in[6];
    const float* b3 = (const float*)d_in[7];
    const float* Wc = (const float*)d_in[8];
    const float* bc = (const float*)d_in[9];

    int N    = in_sizes[0] / H;       // 100000
    int E    = in_sizes[1] / 2;       // 3200000
    int nbk  = (N + 127) >> 7;        // 782 buckets

    const int* srcp = eidx;
    const int* dstp = eidx + E;

    float* out  = (float*)d_out;
    float* hOut = out + (size_t)N * COUT;            // fp32 h output region
    unsigned short* h16 = (unsigned short*)hOut;     // fp16 ping buffer (first half)

    char* p = (char*)d_ws;
    float* hAf      = (float*)p;  p += (size_t)N * H * 4;   // fp16 table lives here (half used)
    int*   col      = (int*)p;    p += (size_t)E * 4;
    int*   rowptr   = (int*)p;    p += (size_t)(N + 1) * 4;
    float* dinv     = (float*)p;  p += (size_t)N * 4;
    int*   bFill    = (int*)p;    p += 1024 * 4;
    unsigned short* hA = (unsigned short*)hAf;
    int*   packed   = (int*)hAf;  // aliases hA: consumed by fine_kernel before gemm1 writes hA

    int gg = (N + 63) / 64;
    int gs = (N + 15) / 16;
    int gb = (E + 8191) / 8192;

    hipMemsetAsync(bFill, 0, (size_t)nbk * 4, stream);
    bin_kernel<<<gb, 256, 0, stream>>>(srcp, dstp, bFill, packed, E, nbk);
    fine_kernel<<<nbk, 256, 0, stream>>>(packed, bFill, rowptr, col, dinv, N, E);

    // layer 1
    gemm128_kernel<<<gg, 256, 0, stream>>>(x, W1, dinv, hA, N);
    spmm_h16_kernel<<<gs, 256, 0, stream>>>(hA, rowptr, col, dinv, b1, h16, N);
    // layer 2
    gemm128f16_kernel<<<gg, 256, 0, stream>>>(h16, W2, dinv, hA, N);
    spmm_h16_kernel<<<gs, 256, 0, stream>>>(hA, rowptr, col, dinv, b2, h16, N);
    // layer 3
    gemm128f16_kernel<<<gg, 256, 0, stream>>>(h16, W3, dinv, hA, N);
    spmm_fused_kernel<<<gs, 256, 0, stream>>>(hA, rowptr, col, dinv, b3, Wc, bc, hOut, out, N);
}